// Round 7
// baseline (435.151 us; speedup 1.0000x reference)
//
#include <hip/hip_runtime.h>
#include <hip/hip_cooperative_groups.h>

namespace cg = cooperative_groups;

// Problem constants
#define NPAR   8192      // parents
#define NCH    65536     // children = NPAR*8
#define RES    32
#define EPS    1e-5f
#define GRIDSZ (512 * 256)

typedef __attribute__((ext_vector_type(8))) short short8;
typedef __attribute__((ext_vector_type(4))) float floatx4;

__device__ __forceinline__ unsigned short f2bf(float f) {
    union { float f; unsigned u; } v; v.f = f;
    unsigned r = v.u + 0x7fffu + ((v.u >> 16) & 1u);   // RNE
    return (unsigned short)(r >> 16);
}
__device__ __forceinline__ float bf2f(unsigned short b) {
    union { unsigned u; float f; } v; v.u = ((unsigned)b) << 16;
    return v.f;
}
// async 16B global->LDS: per-lane global addr, wave-uniform LDS base (+lane*16)
__device__ __forceinline__ void glds16(const void* g, void* l) {
    __builtin_amdgcn_global_load_lds(
        (__attribute__((address_space(1))) const void*)g,
        (__attribute__((address_space(3))) void*)l, 16, 0, 0);
}
// parent-grid tap index for (child-offset o, slot s): e_a = o_a + s_a - 1
__device__ __forceinline__ int k27_of(int o, int s) {
    return (((o >> 2) & 1) + ((s >> 2) & 1)) * 9 +
           (((o >> 1) & 1) + ((s >> 1) & 1)) * 3 +
           ((o & 1) + (s & 1));
}
// fine-tap d-list per axis for (o,s) folding
__device__ __forceinline__ void axis_dlist(int o, int s, int* d, int& n) {
    if (o == 0) { if (s == 0) { d[0] = -1; n = 1; } else { d[0] = 0; d[1] = 1; n = 2; } }
    else        { if (s == 0) { d[0] = -1; d[1] = 0; n = 2; } else { d[0] = 1; n = 1; } }
}

// ---------------------------------------------------------------------------
// Shared MFMA helpers — 1M x 4N wave grid (verified r5: conv2 68->59 µs).
// LDS A layout (per buffer): [grp(8)][ks(4)][r16(16)][cch(4)][8 shorts].
// Bank-conflict fix (verified: SQ_LDS_BANK_CONFLICT 3.54M -> 0): source-side
// XOR cch^((r16>>1)&3), undone on ds_read (swz = quad^((l16>>1)&3)).
__device__ __forceinline__ void mfma_phase(
    const unsigned short* __restrict__ Abuf, short8 (&bfr)[2][4],
    floatx4 (&acc)[8][2], int aswz) {
#pragma unroll
    for (int ks = 0; ks < 4; ++ks) {
        short8 afr[8];
#pragma unroll
        for (int mt = 0; mt < 8; ++mt)
            afr[mt] = *(const short8*)&Abuf[(mt << 11) + (ks << 9) + aswz];
#pragma unroll
        for (int mt = 0; mt < 8; ++mt)
#pragma unroll
            for (int nt = 0; nt < 2; ++nt)
                acc[mt][nt] = __builtin_amdgcn_mfma_f32_16x16x32_bf16(
                    afr[mt], bfr[nt][ks], acc[mt][nt], 0, 0, 0);
    }
}
__device__ __forceinline__ void loadB(const unsigned short* __restrict__ Wtap,
                                      short8 (&bfr)[2][4], int wn, int lane) {
#pragma unroll
    for (int nt = 0; nt < 2; ++nt)
#pragma unroll
        for (int ks = 0; ks < 4; ++ks)
            bfr[nt][ks] = *(const short8*)&Wtap[(((wn * 2 + nt) << 2) + ks) * 512 + (lane << 3)];
}
__device__ __forceinline__ void stageA(const unsigned short* __restrict__ Ag,
                                       int iv0, int iv1, const unsigned short* zsrc,
                                       unsigned short* __restrict__ buf,
                                       int base0, int base1, int cchOff) {
    const unsigned short* g0 = (iv0 >= 0) ? Ag + (long)iv0 * 128 : zsrc;
    const unsigned short* g1 = (iv1 >= 0) ? Ag + (long)iv1 * 128 : zsrc;
#pragma unroll
    for (int i = 0; i < 4; ++i) glds16(g0 + i * 32 + cchOff, &buf[base0 + i * 512]);
#pragma unroll
    for (int i = 0; i < 4; ++i) glds16(g1 + i * 32 + cchOff, &buf[base1 + i * 512]);
}

// ===========================================================================
// FUSED cooperative kernel: the whole pipeline in one launch, phases split by
// grid.sync().  512 blocks x 256 threads = exactly 2 blocks/CU (64 KB LDS).
// Inner structures identical to the r6 5-kernel version (verified best).
__global__ void __launch_bounds__(256, 2) fused_kernel(
    const int* __restrict__ coords, int* __restrict__ grid32,
    const float* __restrict__ feats, float* __restrict__ stats,
    const float* __restrict__ W1, const float* __restrict__ W2,
    unsigned short* __restrict__ Wc1f, unsigned short* __restrict__ Wp2,
    int* __restrict__ idx_tab, int* __restrict__ pidx27,
    const float* __restrict__ gamma1, const float* __restrict__ beta1,
    unsigned short* __restrict__ h0b,
    const float* __restrict__ bias1, unsigned short* __restrict__ h1b,
    const float* __restrict__ gamma2, const float* __restrict__ beta2,
    const float* __restrict__ bias2, float* __restrict__ out,
    const float* __restrict__ zpage) {
    cg::grid_group gg = cg::this_grid();
    __shared__ unsigned short A_lds[2][16384];   // 2 x 32 KB

    const int t = threadIdx.x, b = blockIdx.x;
    const int tid = b * 256 + t;
    float* sum1 = stats;      float* sq1 = stats + 32;
    float* sum2 = stats + 64; float* sq2 = stats + 96;

    // ======== Phase A: grid32 scatter / W2 pack / W1 fold / GN1 stats ======
    if (tid < NPAR) {
        grid32[(coords[tid*3] << 10) + (coords[tid*3+1] << 5) + coords[tid*3+2]] = tid;
    }
    if (tid < 55296) {                       // W2 bf16 pack
        int lane = tid & 63;
        int ks   = (tid >> 6) & 3;
        int nb   = (tid >> 8) & 7;
        int tap  = tid >> 11;                // 0..26
        int n  = nb * 16 + (lane & 15);
        int k0 = ks * 32 + (lane >> 4) * 8;
        unsigned short v[8];
#pragma unroll
        for (int j = 0; j < 8; ++j) v[j] = f2bf(W2[tap * 16384 + (k0 + j) * 128 + n]);
        uint4 pk;
        pk.x = (unsigned)v[0] | ((unsigned)v[1] << 16);
        pk.y = (unsigned)v[2] | ((unsigned)v[3] << 16);
        pk.z = (unsigned)v[4] | ((unsigned)v[5] << 16);
        pk.w = (unsigned)v[6] | ((unsigned)v[7] << 16);
        *(uint4*)&Wp2[(long)tid * 8] = pk;
    }
    {                                        // W1 fold+pack (131072 items)
        int rem = tid;
        int lane  = rem & 63;
        int ks    = (rem >> 6) & 3;
        int nb    = (rem >> 8) & 7;
        int combo = rem >> 11;               // 0..63 = o*8+s
        int o = combo >> 3, s = combo & 7;
        int n  = nb * 16 + (lane & 15);
        int k0 = ks * 32 + (lane >> 4) * 8;
        int d0[2], d1[2], d2[2], n0, n1, n2;
        axis_dlist((o >> 2) & 1, (s >> 2) & 1, d0, n0);
        axis_dlist((o >> 1) & 1, (s >> 1) & 1, d1, n1);
        axis_dlist(o & 1,        s & 1,        d2, n2);
        unsigned short v[8];
#pragma unroll
        for (int j = 0; j < 8; ++j) {
            float acc = 0.0f;
            for (int a = 0; a < n0; ++a)
                for (int bb = 0; bb < n1; ++bb)
                    for (int cc = 0; cc < n2; ++cc) {
                        int kk = (d0[a] + 1) * 9 + (d1[bb] + 1) * 3 + (d2[cc] + 1);
                        acc += W1[kk * 16384 + (k0 + j) * 128 + n];
                    }
            v[j] = f2bf(acc);
        }
        uint4 pk;
        pk.x = (unsigned)v[0] | ((unsigned)v[1] << 16);
        pk.y = (unsigned)v[2] | ((unsigned)v[3] << 16);
        pk.z = (unsigned)v[4] | ((unsigned)v[5] << 16);
        pk.w = (unsigned)v[6] | ((unsigned)v[7] << 16);
        *(uint4*)&Wc1f[(long)rem * 8] = pk;
    }
    {                                        // GN1 stats
        float* s_sum = (float*)(&A_lds[0][0]);
        float* s_sq  = s_sum + 32;
        if (t < 32) { s_sum[t] = 0.0f; s_sq[t] = 0.0f; }
        __syncthreads();
        const float4* x4 = (const float4*)feats;
        int g = tid & 31;
        float ls = 0.0f, lq = 0.0f;
        for (int idx = tid; idx < NPAR * 32; idx += GRIDSZ) {
            float4 v = x4[idx];
            ls += v.x + v.y + v.z + v.w;
            lq += v.x * v.x + v.y * v.y + v.z * v.z + v.w * v.w;
        }
        atomicAdd(&s_sum[g], ls);
        atomicAdd(&s_sq[g], lq);
        __syncthreads();
        if (t < 32) { atomicAdd(&sum1[t], s_sum[t]); atomicAdd(&sq1[t], s_sq[t]); }
        __syncthreads();
    }
    gg.sync();

    // ======== Phase B: idx_tab+pidx27 build / GN1 apply ====================
    if (tid < NPAR) {
        int p = tid;
        int cx = coords[p*3], cy = coords[p*3+1], cz = coords[p*3+2];
        int r27[27];
#pragma unroll
        for (int k = 0; k < 27; ++k) {
            int nx = cx + k / 9 - 1, ny = cy + (k / 3) % 3 - 1, nz = cz + k % 3 - 1;
            int r = -1;
            if ((unsigned)nx < 32u && (unsigned)ny < 32u && (unsigned)nz < 32u) {
                int g = grid32[(nx << 10) + (ny << 5) + nz];
                if ((unsigned)g < (unsigned)NPAR) r = g;
            }
            r27[k] = r;
            pidx27[k * NPAR + p] = r;
        }
#pragma unroll
        for (int k = 0; k < 27; ++k) {
            const int dx = k / 9 - 1, dy = (k / 3) % 3 - 1, dz = k % 3 - 1;
            int v[8];
#pragma unroll
            for (int o = 0; o < 8; ++o) {
                const int ex = ((o >> 2) & 1) + dx;
                const int ey = ((o >> 1) & 1) + dy;
                const int ez = (o & 1) + dz;
                const int ptap = ((ex >> 1) + 1) * 9 + ((ey >> 1) + 1) * 3 + ((ez >> 1) + 1);
                const int slot = ((ex & 1) << 2) + ((ey & 1) << 1) + (ez & 1);
                int r = r27[ptap];
                v[o] = (r >= 0) ? slot * NPAR + r : -1;
            }
            int4* dst = (int4*)&idx_tab[k * NCH + p * 8];
            dst[0] = make_int4(v[0], v[1], v[2], v[3]);
            dst[1] = make_int4(v[4], v[5], v[6], v[7]);
        }
    }
    {                                        // GN1 apply + SiLU -> h0b bf16
        const float4* x4 = (const float4*)feats;
        uint2* y2 = (uint2*)h0b;
        const float4* g4 = (const float4*)gamma1;
        const float4* b4 = (const float4*)beta1;
        float cnt = (float)NPAR * 4.0f;
        for (int idx = tid; idx < NPAR * 32; idx += GRIDSZ) {
            int c4 = idx & 31;
            float mean = sum1[c4] / cnt;
            float var = sq1[c4] / cnt - mean * mean;
            float rstd = rsqrtf(var + EPS);
            float4 v = x4[idx];
            float4 gm = g4[c4];
            float4 bt = b4[c4];
            float a[4] = {v.x, v.y, v.z, v.w};
            float gq[4] = {gm.x, gm.y, gm.z, gm.w};
            float bq[4] = {bt.x, bt.y, bt.z, bt.w};
            unsigned short o[4];
#pragma unroll
            for (int i = 0; i < 4; ++i) {
                float tv = (a[i] - mean) * rstd * gq[i] + bq[i];
                o[i] = f2bf(tv / (1.0f + __expf(-tv)));
            }
            uint2 pk;
            pk.x = (unsigned)o[0] | ((unsigned)o[1] << 16);
            pk.y = (unsigned)o[2] | ((unsigned)o[3] << 16);
            y2[idx] = pk;
        }
    }
    gg.sync();

    // ======== Phase C: CONV1 folded (8 slots) + GN2 stats ==================
    {
        int o  = b & 7;
        int P0 = (b >> 3) << 7;              // 128 parents per block
        const unsigned short* Wb = Wc1f + ((long)o << 17);
        int wv = t >> 6, lane = t & 63, quad = lane >> 4, l16 = lane & 15;
        int wn = wv;                          // 1M x 4N
        int r16 = lane >> 2, cch = lane & 3;
        int c0 = wv * 2, c1 = wv * 2 + 1;
        int row0 = ((c0 >> 2) << 6) + ((c0 & 3) << 4) + r16;
        int row1 = ((c1 >> 2) << 6) + ((c1 & 3) << 4) + r16;
        int base0 = ((c0 >> 2) << 13) + ((c0 & 3) << 11);
        int base1 = ((c1 >> 2) << 13) + ((c1 & 3) << 11);
        int cchOff = (cch ^ ((r16 >> 1) & 3)) << 3;
        int aswz = (l16 << 5) + ((quad ^ ((l16 >> 1) & 3)) << 3);
        const unsigned short* zsrc = (const unsigned short*)zpage;

        floatx4 acc[8][2];
#pragma unroll
        for (int mt = 0; mt < 8; ++mt)
#pragma unroll
            for (int nt = 0; nt < 2; ++nt)
                acc[mt][nt] = (floatx4){0.f, 0.f, 0.f, 0.f};
        short8 bA[2][4], bB[2][4];

        stageA(h0b, pidx27[k27_of(o, 0) * NPAR + P0 + row0],
                    pidx27[k27_of(o, 0) * NPAR + P0 + row1], zsrc, A_lds[0], base0, base1, cchOff);
        loadB(Wb, bA, wn, lane);
        int nv0 = pidx27[k27_of(o, 1) * NPAR + P0 + row0];
        int nv1 = pidx27[k27_of(o, 1) * NPAR + P0 + row1];
        __syncthreads();

#pragma unroll 1
        for (int s = 0; s < 8; s += 2) {
            stageA(h0b, nv0, nv1, zsrc, A_lds[1], base0, base1, cchOff);
            loadB(Wb + ((long)(s + 1) << 14), bB, wn, lane);
            if (s + 2 < 8) {
                nv0 = pidx27[k27_of(o, s + 2) * NPAR + P0 + row0];
                nv1 = pidx27[k27_of(o, s + 2) * NPAR + P0 + row1];
            }
            mfma_phase(A_lds[0], bA, acc, aswz);
            __syncthreads();
            if (s + 2 < 8) {
                stageA(h0b, nv0, nv1, zsrc, A_lds[0], base0, base1, cchOff);
                loadB(Wb + ((long)(s + 2) << 14), bA, wn, lane);
                if (s + 3 < 8) {
                    nv0 = pidx27[k27_of(o, s + 3) * NPAR + P0 + row0];
                    nv1 = pidx27[k27_of(o, s + 3) * NPAR + P0 + row1];
                }
            }
            mfma_phase(A_lds[1], bB, acc, aswz);
            __syncthreads();
        }

        // epilogue: bias + bf16 + GN2 stats -> LDS bounce -> coalesced stores
        unsigned short* lds_s = (unsigned short*)A_lds;   // 32 KB (buf 0)
        float* sred = (float*)(&A_lds[1][0]);             // 64 f (buf 1)
        float s_[2] = {0.f, 0.f}, q_[2] = {0.f, 0.f};
#pragma unroll
        for (int nt = 0; nt < 2; ++nt) {
            int col = wn * 32 + nt * 16 + l16;
            float bv = bias1[col];
#pragma unroll
            for (int mt = 0; mt < 8; ++mt) {
#pragma unroll
                for (int r = 0; r < 4; ++r) {
                    int row = mt * 16 + quad * 4 + r;
                    float v = acc[mt][nt][r] + bv;
                    unsigned short u = f2bf(v);
                    lds_s[row * 128 + (col ^ (quad << 4))] = u;
                    float vr = bf2f(u);
                    s_[nt] += vr;
                    q_[nt] += vr * vr;
                }
            }
        }
        if (t < 64) sred[t] = 0.0f;
        __syncthreads();
#pragma unroll
        for (int it = 0; it < 8; ++it) {
            int f = it * 256 + t;
            int row = f >> 4, c = (f & 15) * 8;
            int sw = ((row >> 2) & 3) << 4;
            uint4 v = *(const uint4*)&lds_s[row * 128 + (c ^ sw)];
            *(uint4*)&h1b[((long)o * NPAR + P0 + row) * 128 + c] = v;
        }
#pragma unroll
        for (int nt = 0; nt < 2; ++nt) {
            int g = (wn * 32 + nt * 16 + l16) >> 2;
            atomicAdd(&sred[g], s_[nt]);
            atomicAdd(&sred[32 + g], q_[nt]);
        }
        __syncthreads();
        if (t < 32) { atomicAdd(&sum2[t], sred[t]); atomicAdd(&sq2[t], sred[32 + t]); }
        __syncthreads();
    }
    gg.sync();

    // ======== Phase D: GN2 apply + SiLU (in place on h1b) ==================
    {
        uint2* x2 = (uint2*)h1b;
        const float4* g4 = (const float4*)gamma2;
        const float4* b4 = (const float4*)beta2;
        float cnt = (float)NCH * 4.0f;
        for (int idx = tid; idx < NCH * 32; idx += GRIDSZ) {
            int c4 = idx & 31;
            float mean = sum2[c4] / cnt;
            float var = sq2[c4] / cnt - mean * mean;
            float rstd = rsqrtf(var + EPS);
            uint2 pk = x2[idx];
            float a[4] = {bf2f((unsigned short)(pk.x & 0xffff)), bf2f((unsigned short)(pk.x >> 16)),
                          bf2f((unsigned short)(pk.y & 0xffff)), bf2f((unsigned short)(pk.y >> 16))};
            float4 gm = g4[c4];
            float4 bt = b4[c4];
            float gq[4] = {gm.x, gm.y, gm.z, gm.w};
            float bq[4] = {bt.x, bt.y, bt.z, bt.w};
            unsigned short o[4];
#pragma unroll
            for (int i = 0; i < 4; ++i) {
                float tv = (a[i] - mean) * rstd * gq[i] + bq[i];
                o[i] = f2bf(tv / (1.0f + __expf(-tv)));
            }
            pk.x = (unsigned)o[0] | ((unsigned)o[1] << 16);
            pk.y = (unsigned)o[2] | ((unsigned)o[3] << 16);
            x2[idx] = pk;
        }
    }
    gg.sync();

    // ======== Phase E: CONV2 (27 taps) + residual ==========================
    {
        int R0 = b * 128;
        int wv = t >> 6, lane = t & 63, quad = lane >> 4, l16 = lane & 15;
        int wn = wv;
        int r16 = lane >> 2, cch = lane & 3;
        int c0 = wv * 2, c1 = wv * 2 + 1;
        int row0 = ((c0 >> 2) << 6) + ((c0 & 3) << 4) + r16;
        int row1 = ((c1 >> 2) << 6) + ((c1 & 3) << 4) + r16;
        int base0 = ((c0 >> 2) << 13) + ((c0 & 3) << 11);
        int base1 = ((c1 >> 2) << 13) + ((c1 & 3) << 11);
        int cchOff = (cch ^ ((r16 >> 1) & 3)) << 3;
        int aswz = (l16 << 5) + ((quad ^ ((l16 >> 1) & 3)) << 3);
        const unsigned short* zsrc = (const unsigned short*)zpage;

        floatx4 acc[8][2];
#pragma unroll
        for (int mt = 0; mt < 8; ++mt)
#pragma unroll
            for (int nt = 0; nt < 2; ++nt)
                acc[mt][nt] = (floatx4){0.f, 0.f, 0.f, 0.f};
        short8 bA[2][4], bB[2][4];

        stageA(h1b, idx_tab[R0 + row0], idx_tab[R0 + row1], zsrc, A_lds[0], base0, base1, cchOff);
        loadB(Wp2, bA, wn, lane);
        int nv0 = idx_tab[NCH + R0 + row0], nv1 = idx_tab[NCH + R0 + row1];
        __syncthreads();

#pragma unroll 1
        for (int k = 0; k < 27; k += 2) {
            if (k + 1 < 27) {
                stageA(h1b, nv0, nv1, zsrc, A_lds[1], base0, base1, cchOff);
                loadB(Wp2 + ((long)(k + 1) << 14), bB, wn, lane);
                if (k + 2 < 27) {
                    nv0 = idx_tab[(k + 2) * NCH + R0 + row0];
                    nv1 = idx_tab[(k + 2) * NCH + R0 + row1];
                }
            }
            mfma_phase(A_lds[0], bA, acc, aswz);
            __syncthreads();
            if (k + 1 < 27) {
                if (k + 2 < 27) {
                    stageA(h1b, nv0, nv1, zsrc, A_lds[0], base0, base1, cchOff);
                    loadB(Wp2 + ((long)(k + 2) << 14), bA, wn, lane);
                    if (k + 3 < 27) {
                        nv0 = idx_tab[(k + 3) * NCH + R0 + row0];
                        nv1 = idx_tab[(k + 3) * NCH + R0 + row1];
                    }
                }
                mfma_phase(A_lds[1], bB, acc, aswz);
                __syncthreads();
            }
        }

        // epilogue: bias + resid -> LDS bounce -> coalesced float4
        float* lds_f = (float*)A_lds;        // 64 KB = 128x128 fp32 exact
#pragma unroll
        for (int nt = 0; nt < 2; ++nt) {
            int col = wn * 32 + nt * 16 + l16;
            float bv = bias2[col];
#pragma unroll
            for (int mt = 0; mt < 8; ++mt) {
#pragma unroll
                for (int r = 0; r < 4; ++r) {
                    int row = mt * 16 + quad * 4 + r;
                    long R = (long)R0 + row;
                    float v = acc[mt][nt][r] + bv + feats[(R >> 3) * 128 + col];
                    lds_f[row * 128 + (col ^ (quad << 4))] = v;
                }
            }
        }
        __syncthreads();
#pragma unroll
        for (int it = 0; it < 16; ++it) {
            int f = it * 256 + t;
            int row = f >> 5, c = (f & 31) * 4;
            int sw = ((row >> 2) & 3) << 4;
            float4 v = *(const float4*)&lds_f[row * 128 + (c ^ sw)];
            *(float4*)&out[((long)R0 + row) * 128 + c] = v;
        }
    }
}

// ===========================================================================
// Fallback path (r6-verified 5-kernel pipeline) in case cooperative launch is
// refused by the runtime/graph-capture.
__global__ void k1_kernel(const int* __restrict__ coords, int* __restrict__ grid32,
                          const float* __restrict__ x, float* __restrict__ sum,
                          float* __restrict__ sq,
                          const float* __restrict__ W1, const float* __restrict__ W2,
                          unsigned short* __restrict__ Wc1f, unsigned short* __restrict__ Wp2) {
    int b = blockIdx.x;
    int t = threadIdx.x;
    if (b < 32) {
        int p = b * 256 + t;
        grid32[(coords[p*3] << 10) + (coords[p*3+1] << 5) + coords[p*3+2]] = p;
    } else if (b < 248) {
        int rem = (b - 32) * 256 + t;
        int lane = rem & 63;
        int ks   = (rem >> 6) & 3;
        int nb   = (rem >> 8) & 7;
        int tap  = rem >> 11;
        int n  = nb * 16 + (lane & 15);
        int k0 = ks * 32 + (lane >> 4) * 8;
        unsigned short v[8];
#pragma unroll
        for (int j = 0; j < 8; ++j) v[j] = f2bf(W2[tap * 16384 + (k0 + j) * 128 + n]);
        uint4 pk;
        pk.x = (unsigned)v[0] | ((unsigned)v[1] << 16);
        pk.y = (unsigned)v[2] | ((unsigned)v[3] << 16);
        pk.z = (unsigned)v[4] | ((unsigned)v[5] << 16);
        pk.w = (unsigned)v[6] | ((unsigned)v[7] << 16);
        *(uint4*)&Wp2[(long)rem * 8] = pk;
    } else if (b < 760) {
        int rem = (b - 248) * 256 + t;
        int lane  = rem & 63;
        int ks    = (rem >> 6) & 3;
        int nb    = (rem >> 8) & 7;
        int combo = rem >> 11;
        int o = combo >> 3, s = combo & 7;
        int n  = nb * 16 + (lane & 15);
        int k0 = ks * 32 + (lane >> 4) * 8;
        int d0[2], d1[2], d2[2], n0, n1, n2;
        axis_dlist((o >> 2) & 1, (s >> 2) & 1, d0, n0);
        axis_dlist((o >> 1) & 1, (s >> 1) & 1, d1, n1);
        axis_dlist(o & 1,        s & 1,        d2, n2);
        unsigned short v[8];
#pragma unroll
        for (int j = 0; j < 8; ++j) {
            float acc = 0.0f;
            for (int a = 0; a < n0; ++a)
                for (int bb = 0; bb < n1; ++bb)
                    for (int cc = 0; cc < n2; ++cc) {
                        int kk = (d0[a] + 1) * 9 + (d1[bb] + 1) * 3 + (d2[cc] + 1);
                        acc += W1[kk * 16384 + (k0 + j) * 128 + n];
                    }
            v[j] = f2bf(acc);
        }
        uint4 pk;
        pk.x = (unsigned)v[0] | ((unsigned)v[1] << 16);
        pk.y = (unsigned)v[2] | ((unsigned)v[3] << 16);
        pk.z = (unsigned)v[4] | ((unsigned)v[5] << 16);
        pk.w = (unsigned)v[6] | ((unsigned)v[7] << 16);
        *(uint4*)&Wc1f[(long)rem * 8] = pk;
    } else {
        __shared__ float s_sum[32], s_sq[32];
        if (t < 32) { s_sum[t] = 0.0f; s_sq[t] = 0.0f; }
        __syncthreads();
        const float4* x4 = (const float4*)x;
        int total = NPAR * 32;
        int idx0 = (b - 760) * 256 + t;
        int g = idx0 & 31;
        float ls = 0.0f, lq = 0.0f;
        for (int idx = idx0; idx < total; idx += 256 * 256) {
            float4 v = x4[idx];
            ls += v.x + v.y + v.z + v.w;
            lq += v.x * v.x + v.y * v.y + v.z * v.z + v.w * v.w;
        }
        atomicAdd(&s_sum[g], ls);
        atomicAdd(&s_sq[g], lq);
        __syncthreads();
        if (t < 32) { atomicAdd(&sum[t], s_sum[t]); atomicAdd(&sq[t], s_sq[t]); }
    }
}

__global__ void k2_kernel(const int* __restrict__ coords, const int* __restrict__ grid32,
                          int* __restrict__ idx_tab, int* __restrict__ pidx27,
                          const float* __restrict__ x, const float* __restrict__ sum,
                          const float* __restrict__ sq, const float* __restrict__ gamma,
                          const float* __restrict__ beta, unsigned short* __restrict__ y) {
    int b = blockIdx.x;
    if (b < 32) {
        int p = b * 256 + threadIdx.x;
        int cx = coords[p*3], cy = coords[p*3+1], cz = coords[p*3+2];
        int r27[27];
#pragma unroll
        for (int k = 0; k < 27; ++k) {
            int nx = cx + k / 9 - 1, ny = cy + (k / 3) % 3 - 1, nz = cz + k % 3 - 1;
            int r = -1;
            if ((unsigned)nx < 32u && (unsigned)ny < 32u && (unsigned)nz < 32u) {
                int g = grid32[(nx << 10) + (ny << 5) + nz];
                if ((unsigned)g < (unsigned)NPAR) r = g;
            }
            r27[k] = r;
            pidx27[k * NPAR + p] = r;
        }
#pragma unroll
        for (int k = 0; k < 27; ++k) {
            const int dx = k / 9 - 1, dy = (k / 3) % 3 - 1, dz = k % 3 - 1;
            int v[8];
#pragma unroll
            for (int o = 0; o < 8; ++o) {
                const int ex = ((o >> 2) & 1) + dx;
                const int ey = ((o >> 1) & 1) + dy;
                const int ez = (o & 1) + dz;
                const int ptap = ((ex >> 1) + 1) * 9 + ((ey >> 1) + 1) * 3 + ((ez >> 1) + 1);
                const int slot = ((ex & 1) << 2) + ((ey & 1) << 1) + (ez & 1);
                int r = r27[ptap];
                v[o] = (r >= 0) ? slot * NPAR + r : -1;
            }
            int4* dst = (int4*)&idx_tab[k * NCH + p * 8];
            dst[0] = make_int4(v[0], v[1], v[2], v[3]);
            dst[1] = make_int4(v[4], v[5], v[6], v[7]);
        }
    } else {
        const float4* x4 = (const float4*)x;
        uint2* y2 = (uint2*)y;
        const float4* g4 = (const float4*)gamma;
        const float4* b4 = (const float4*)beta;
        float cnt = (float)NPAR * 4.0f;
        int total = NPAR * 32;
        for (int idx = (b - 32) * 256 + threadIdx.x; idx < total; idx += 256 * 256) {
            int c4 = idx & 31;
            float mean = sum[c4] / cnt;
            float var = sq[c4] / cnt - mean * mean;
            float rstd = rsqrtf(var + EPS);
            float4 v = x4[idx];
            float4 gm = g4[c4];
            float4 bt = b4[c4];
            float a[4] = {v.x, v.y, v.z, v.w};
            float gg[4] = {gm.x, gm.y, gm.z, gm.w};
            float bb[4] = {bt.x, bt.y, bt.z, bt.w};
            unsigned short o[4];
#pragma unroll
            for (int i = 0; i < 4; ++i) {
                float tv = (a[i] - mean) * rstd * gg[i] + bb[i];
                o[i] = f2bf(tv / (1.0f + __expf(-tv)));
            }
            uint2 pk;
            pk.x = (unsigned)o[0] | ((unsigned)o[1] << 16);
            pk.y = (unsigned)o[2] | ((unsigned)o[3] << 16);
            y2[idx] = pk;
        }
    }
}

__global__ void gn_apply_bf16_kernel(unsigned short* __restrict__ x,
                                     const float* __restrict__ sum, const float* __restrict__ sq,
                                     const float* __restrict__ gamma, const float* __restrict__ beta,
                                     int nrows) {
    uint2* x2 = (uint2*)x;
    const float4* g4 = (const float4*)gamma;
    const float4* b4 = (const float4*)beta;
    float cnt = (float)nrows * 4.0f;
    int total = nrows * 32;
    for (int idx = blockIdx.x * blockDim.x + threadIdx.x; idx < total;
         idx += gridDim.x * blockDim.x) {
        int c4 = idx & 31;
        float mean = sum[c4] / cnt;
        float var = sq[c4] / cnt - mean * mean;
        float rstd = rsqrtf(var + EPS);
        uint2 pk = x2[idx];
        float a[4] = {bf2f((unsigned short)(pk.x & 0xffff)), bf2f((unsigned short)(pk.x >> 16)),
                      bf2f((unsigned short)(pk.y & 0xffff)), bf2f((unsigned short)(pk.y >> 16))};
        float4 gm = g4[c4];
        float4 bt = b4[c4];
        float gg[4] = {gm.x, gm.y, gm.z, gm.w};
        float bb[4] = {bt.x, bt.y, bt.z, bt.w};
        unsigned short o[4];
#pragma unroll
        for (int i = 0; i < 4; ++i) {
            float tv = (a[i] - mean) * rstd * gg[i] + bb[i];
            o[i] = f2bf(tv / (1.0f + __expf(-tv)));
        }
        pk.x = (unsigned)o[0] | ((unsigned)o[1] << 16);
        pk.y = (unsigned)o[2] | ((unsigned)o[3] << 16);
        x2[idx] = pk;
    }
}

__global__ void __launch_bounds__(256, 2) conv1_fold_kernel(
    const unsigned short* __restrict__ Ag, const unsigned short* __restrict__ Wc1f,
    const float* __restrict__ bias, const int* __restrict__ pidx27,
    unsigned short* __restrict__ outp, const float* __restrict__ zpage,
    float* __restrict__ gsum, float* __restrict__ gsq) {
    __shared__ unsigned short A_lds[2][16384];

    int t = threadIdx.x;
    int o  = blockIdx.x & 7;
    int P0 = (blockIdx.x >> 3) << 7;
    const unsigned short* Wb = Wc1f + ((long)o << 17);
    int wv = t >> 6, lane = t & 63, quad = lane >> 4, l16 = lane & 15;
    int wn = wv;
    int r16 = lane >> 2, cch = lane & 3;
    int c0 = wv * 2, c1 = wv * 2 + 1;
    int row0 = ((c0 >> 2) << 6) + ((c0 & 3) << 4) + r16;
    int row1 = ((c1 >> 2) << 6) + ((c1 & 3) << 4) + r16;
    int base0 = ((c0 >> 2) << 13) + ((c0 & 3) << 11);
    int base1 = ((c1 >> 2) << 13) + ((c1 & 3) << 11);
    int cchOff = (cch ^ ((r16 >> 1) & 3)) << 3;
    int aswz = (l16 << 5) + ((quad ^ ((l16 >> 1) & 3)) << 3);
    const unsigned short* zsrc = (const unsigned short*)zpage;

    floatx4 acc[8][2];
#pragma unroll
    for (int mt = 0; mt < 8; ++mt)
#pragma unroll
        for (int nt = 0; nt < 2; ++nt)
            acc[mt][nt] = (floatx4){0.f, 0.f, 0.f, 0.f};
    short8 bA[2][4], bB[2][4];

    stageA(Ag, pidx27[k27_of(o, 0) * NPAR + P0 + row0],
               pidx27[k27_of(o, 0) * NPAR + P0 + row1], zsrc, A_lds[0], base0, base1, cchOff);
    loadB(Wb, bA, wn, lane);
    int nv0 = pidx27[k27_of(o, 1) * NPAR + P0 + row0];
    int nv1 = pidx27[k27_of(o, 1) * NPAR + P0 + row1];
    __syncthreads();

#pragma unroll 1
    for (int s = 0; s < 8; s += 2) {
        stageA(Ag, nv0, nv1, zsrc, A_lds[1], base0, base1, cchOff);
        loadB(Wb + ((long)(s + 1) << 14), bB, wn, lane);
        if (s + 2 < 8) {
            nv0 = pidx27[k27_of(o, s + 2) * NPAR + P0 + row0];
            nv1 = pidx27[k27_of(o, s + 2) * NPAR + P0 + row1];
        }
        mfma_phase(A_lds[0], bA, acc, aswz);
        __syncthreads();
        if (s + 2 < 8) {
            stageA(Ag, nv0, nv1, zsrc, A_lds[0], base0, base1, cchOff);
            loadB(Wb + ((long)(s + 2) << 14), bA, wn, lane);
            if (s + 3 < 8) {
                nv0 = pidx27[k27_of(o, s + 3) * NPAR + P0 + row0];
                nv1 = pidx27[k27_of(o, s + 3) * NPAR + P0 + row1];
            }
        }
        mfma_phase(A_lds[1], bB, acc, aswz);
        __syncthreads();
    }

    unsigned short* lds_s = (unsigned short*)A_lds;
    float* sred = (float*)(&A_lds[1][0]);
    float s_[2] = {0.f, 0.f}, q_[2] = {0.f, 0.f};
#pragma unroll
    for (int nt = 0; nt < 2; ++nt) {
        int col = wn * 32 + nt * 16 + l16;
        float bv = bias[col];
#pragma unroll
        for (int mt = 0; mt < 8; ++mt) {
#pragma unroll
            for (int r = 0; r < 4; ++r) {
                int row = mt * 16 + quad * 4 + r;
                float v = acc[mt][nt][r] + bv;
                unsigned short u = f2bf(v);
                lds_s[row * 128 + (col ^ (quad << 4))] = u;
                float vr = bf2f(u);
                s_[nt] += vr;
                q_[nt] += vr * vr;
            }
        }
    }
    if (t < 64) sred[t] = 0.0f;
    __syncthreads();
#pragma unroll
    for (int it = 0; it < 8; ++it) {
        int f = it * 256 + t;
        int row = f >> 4, c = (f & 15) * 8;
        int sw = ((row >> 2) & 3) << 4;
        uint4 v = *(const uint4*)&lds_s[row * 128 + (c ^ sw)];
        *(uint4*)&outp[((long)o * NPAR + P0 + row) * 128 + c] = v;
    }
#pragma unroll
    for (int nt = 0; nt < 2; ++nt) {
        int g = (wn * 32 + nt * 16 + l16) >> 2;
        atomicAdd(&sred[g], s_[nt]);
        atomicAdd(&sred[32 + g], q_[nt]);
    }
    __syncthreads();
    if (t < 32) { atomicAdd(&gsum[t], sred[t]); atomicAdd(&gsq[t], sred[32 + t]); }
}

__global__ void __launch_bounds__(256, 2) conv2_kernel(
    const unsigned short* __restrict__ Ag, const unsigned short* __restrict__ Wp,
    const float* __restrict__ bias, const int* __restrict__ idx_tab,
    const float* __restrict__ resid, float* __restrict__ outp,
    const float* __restrict__ zpage) {
    __shared__ unsigned short A_lds[2][16384];

    int t = threadIdx.x;
    int R0 = blockIdx.x * 128;
    int wv = t >> 6, lane = t & 63, quad = lane >> 4, l16 = lane & 15;
    int wn = wv;
    int r16 = lane >> 2, cch = lane & 3;
    int c0 = wv * 2, c1 = wv * 2 + 1;
    int row0 = ((c0 >> 2) << 6) + ((c0 & 3) << 4) + r16;
    int row1 = ((c1 >> 2) << 6) + ((c1 & 3) << 4) + r16;
    int base0 = ((c0 >> 2) << 13) + ((c0 & 3) << 11);
    int base1 = ((c1 >> 2) << 13) + ((c1 & 3) << 11);
    int cchOff = (cch ^ ((r16 >> 1) & 3)) << 3;
    int aswz = (l16 << 5) + ((quad ^ ((l16 >> 1) & 3)) << 3);
    const unsigned short* zsrc = (const unsigned short*)zpage;

    floatx4 acc[8][2];
#pragma unroll
    for (int mt = 0; mt < 8; ++mt)
#pragma unroll
        for (int nt = 0; nt < 2; ++nt)
            acc[mt][nt] = (floatx4){0.f, 0.f, 0.f, 0.f};
    short8 bA[2][4], bB[2][4];

    stageA(Ag, idx_tab[R0 + row0], idx_tab[R0 + row1], zsrc, A_lds[0], base0, base1, cchOff);
    loadB(Wp, bA, wn, lane);
    int nv0 = idx_tab[NCH + R0 + row0], nv1 = idx_tab[NCH + R0 + row1];
    __syncthreads();

#pragma unroll 1
    for (int k = 0; k < 27; k += 2) {
        if (k + 1 < 27) {
            stageA(Ag, nv0, nv1, zsrc, A_lds[1], base0, base1, cchOff);
            loadB(Wp + ((long)(k + 1) << 14), bB, wn, lane);
            if (k + 2 < 27) {
                nv0 = idx_tab[(k + 2) * NCH + R0 + row0];
                nv1 = idx_tab[(k + 2) * NCH + R0 + row1];
            }
        }
        mfma_phase(A_lds[0], bA, acc, aswz);
        __syncthreads();
        if (k + 1 < 27) {
            if (k + 2 < 27) {
                stageA(Ag, nv0, nv1, zsrc, A_lds[0], base0, base1, cchOff);
                loadB(Wp + ((long)(k + 2) << 14), bA, wn, lane);
                if (k + 3 < 27) {
                    nv0 = idx_tab[(k + 3) * NCH + R0 + row0];
                    nv1 = idx_tab[(k + 3) * NCH + R0 + row1];
                }
            }
            mfma_phase(A_lds[1], bB, acc, aswz);
            __syncthreads();
        }
    }

    float* lds_f = (float*)A_lds;
#pragma unroll
    for (int nt = 0; nt < 2; ++nt) {
        int col = wn * 32 + nt * 16 + l16;
        float bv = bias[col];
#pragma unroll
        for (int mt = 0; mt < 8; ++mt) {
#pragma unroll
            for (int r = 0; r < 4; ++r) {
                int row = mt * 16 + quad * 4 + r;
                long R = (long)R0 + row;
                float v = acc[mt][nt][r] + bv + resid[(R >> 3) * 128 + col];
                lds_f[row * 128 + (col ^ (quad << 4))] = v;
            }
        }
    }
    __syncthreads();
#pragma unroll
    for (int it = 0; it < 16; ++it) {
        int f = it * 256 + t;
        int row = f >> 5, c = (f & 31) * 4;
        int sw = ((row >> 2) & 3) << 4;
        float4 v = *(const float4*)&lds_f[row * 128 + (c ^ sw)];
        *(float4*)&outp[((long)R0 + row) * 128 + c] = v;
    }
}

// ---------------------------------------------------------------------------
extern "C" void kernel_launch(void* const* d_in, const int* in_sizes, int n_in,
                              void* d_out, int out_size, void* d_ws, size_t ws_size,
                              hipStream_t stream) {
    const float* feats  = (const float*)d_in[0];
    const float* gamma1 = (const float*)d_in[1];
    const float* beta1  = (const float*)d_in[2];
    const float* W1     = (const float*)d_in[3];
    const float* b1     = (const float*)d_in[4];
    const float* gamma2 = (const float*)d_in[5];
    const float* beta2  = (const float*)d_in[6];
    const float* W2     = (const float*)d_in[7];
    const float* b2     = (const float*)d_in[8];
    const int*   coords = (const int*)d_in[9];
    float* out = (float*)d_out;   // 65536 x 128 fp32

    char* ws = (char*)d_ws;
    unsigned short* h0b  = (unsigned short*)(ws);                    // 2 MB
    unsigned short* h1b  = (unsigned short*)(ws + (2u << 20));       // 16 MB, (o,p) layout
    unsigned short* Wc1f = (unsigned short*)(ws + (18u << 20));      // 2 MB
    unsigned short* Wp2  = (unsigned short*)(ws + (20u << 20));      // 864 KB
    int*   grid32        = (int*)  (ws + (21u << 20));               // 128 KB
    float* stats         = (float*)(ws + (21u << 20) + 131072);      // 512 B
    float* zpage         = (float*)(ws + (21u << 20) + 131072 + 512);// 512 B
    int*   idx_tab       = (int*)  (ws + (22u << 20));               // 7.08 MB
    int*   pidx27        = (int*)  (ws + (30u << 20));               // 864 KB

    // zero stats (128 f) + zpage (128 f) in one async memset
    hipMemsetAsync(stats, 0, 1024, stream);

    // --- preferred: single fused cooperative kernel (512 blocks = 2/CU) ---
    void* args[] = {
        (void*)&coords, (void*)&grid32, (void*)&feats, (void*)&stats,
        (void*)&W1, (void*)&W2, (void*)&Wc1f, (void*)&Wp2,
        (void*)&idx_tab, (void*)&pidx27,
        (void*)&gamma1, (void*)&beta1, (void*)&h0b,
        (void*)&b1, (void*)&h1b,
        (void*)&gamma2, (void*)&beta2,
        (void*)&b2, (void*)&out, (void*)&zpage
    };
    hipError_t e = hipLaunchCooperativeKernel(
        reinterpret_cast<const void*>(fused_kernel),
        dim3(512), dim3(256), args, 0, stream);
    if (e == hipSuccess) return;

    // --- fallback: r6-verified 5-kernel pipeline ---
    k1_kernel<<<1016, 256, 0, stream>>>(coords, grid32, feats, stats + 0, stats + 32,
                                        W1, W2, Wc1f, Wp2);
    k2_kernel<<<288, 256, 0, stream>>>(coords, grid32, idx_tab, pidx27,
                                       feats, stats + 0, stats + 32, gamma1, beta1, h0b);
    conv1_fold_kernel<<<8 * (NPAR / 128), 256, 0, stream>>>(h0b, Wc1f, b1, pidx27,
                                                            h1b, zpage,
                                                            stats + 64, stats + 96);
    gn_apply_bf16_kernel<<<1024, 256, 0, stream>>>(h1b, stats + 64, stats + 96, gamma2, beta2, NCH);
    conv2_kernel<<<NCH / 128, 256, 0, stream>>>(h1b, Wp2, b2, idx_tab,
                                                feats, out, zpage);
}

// Round 8
// 188.512 us; speedup vs baseline: 2.3083x; 2.3083x over previous
//
#include <hip/hip_runtime.h>

// Problem constants
#define NPAR   8192      // parents
#define NCH    65536     // children = NPAR*8
#define RES    32
#define EPS    1e-5f

typedef __attribute__((ext_vector_type(8))) short short8;
typedef __attribute__((ext_vector_type(4))) float floatx4;

__device__ __forceinline__ unsigned short f2bf(float f) {
    union { float f; unsigned u; } v; v.f = f;
    unsigned r = v.u + 0x7fffu + ((v.u >> 16) & 1u);   // RNE
    return (unsigned short)(r >> 16);
}
__device__ __forceinline__ float bf2f(unsigned short b) {
    union { unsigned u; float f; } v; v.u = ((unsigned)b) << 16;
    return v.f;
}
// async 16B global->LDS: per-lane global addr, wave-uniform LDS base (+lane*16)
__device__ __forceinline__ void glds16(const void* g, void* l) {
    __builtin_amdgcn_global_load_lds(
        (__attribute__((address_space(1))) const void*)g,
        (__attribute__((address_space(3))) void*)l, 16, 0, 0);
}
// parent-grid tap index for (child-offset o, slot s): e_a = o_a + s_a - 1
__device__ __forceinline__ int k27_of(int o, int s) {
    return (((o >> 2) & 1) + ((s >> 2) & 1)) * 9 +
           (((o >> 1) & 1) + ((s >> 1) & 1)) * 3 +
           ((o & 1) + (s & 1));
}
// fine-tap d-list per axis for (o,s) folding
__device__ __forceinline__ void axis_dlist(int o, int s, int* d, int& n) {
    if (o == 0) { if (s == 0) { d[0] = -1; n = 1; } else { d[0] = 0; d[1] = 1; n = 2; } }
    else        { if (s == 0) { d[0] = -1; d[1] = 0; n = 2; } else { d[0] = 1; n = 1; } }
}

// ---------------------------------------------------------------------------
// Stats are banked 8-way (sum[8][32]) to cut atomic contention per address
// (was 512 serialized RMWs/address in conv1's tail; now 64).  Consumers sum
// the 8 partials once per block into an LDS mean/rstd table.

// ---------------------------------------------------------------------------
// K1, 1016 blocks: grid32 scatter / W2 pack / W1 fold+pack / GN1 stats.
__global__ void k1_kernel(const int* __restrict__ coords, int* __restrict__ grid32,
                          const float* __restrict__ x, float* __restrict__ sum,
                          float* __restrict__ sq,
                          const float* __restrict__ W1, const float* __restrict__ W2,
                          unsigned short* __restrict__ Wc1f, unsigned short* __restrict__ Wp2) {
    int b = blockIdx.x;
    int t = threadIdx.x;
    if (b < 32) {
        int p = b * 256 + t;
        grid32[(coords[p*3] << 10) + (coords[p*3+1] << 5) + coords[p*3+2]] = p;
    } else if (b < 248) {
        int rem = (b - 32) * 256 + t;             // < 55296
        int lane = rem & 63;
        int ks   = (rem >> 6) & 3;
        int nb   = (rem >> 8) & 7;
        int tap  = rem >> 11;                       // 0..26
        int n  = nb * 16 + (lane & 15);
        int k0 = ks * 32 + (lane >> 4) * 8;
        unsigned short v[8];
#pragma unroll
        for (int j = 0; j < 8; ++j) v[j] = f2bf(W2[tap * 16384 + (k0 + j) * 128 + n]);
        uint4 pk;
        pk.x = (unsigned)v[0] | ((unsigned)v[1] << 16);
        pk.y = (unsigned)v[2] | ((unsigned)v[3] << 16);
        pk.z = (unsigned)v[4] | ((unsigned)v[5] << 16);
        pk.w = (unsigned)v[6] | ((unsigned)v[7] << 16);
        *(uint4*)&Wp2[(long)rem * 8] = pk;
    } else if (b < 760) {
        int rem = (b - 248) * 256 + t;            // < 131072
        int lane  = rem & 63;
        int ks    = (rem >> 6) & 3;
        int nb    = (rem >> 8) & 7;
        int combo = rem >> 11;                      // 0..63 = o*8+s
        int o = combo >> 3, s = combo & 7;
        int n  = nb * 16 + (lane & 15);
        int k0 = ks * 32 + (lane >> 4) * 8;
        int d0[2], d1[2], d2[2], n0, n1, n2;
        axis_dlist((o >> 2) & 1, (s >> 2) & 1, d0, n0);
        axis_dlist((o >> 1) & 1, (s >> 1) & 1, d1, n1);
        axis_dlist(o & 1,        s & 1,        d2, n2);
        unsigned short v[8];
#pragma unroll
        for (int j = 0; j < 8; ++j) {
            float acc = 0.0f;
            for (int a = 0; a < n0; ++a)
                for (int bb = 0; bb < n1; ++bb)
                    for (int cc = 0; cc < n2; ++cc) {
                        int kk = (d0[a] + 1) * 9 + (d1[bb] + 1) * 3 + (d2[cc] + 1);
                        acc += W1[kk * 16384 + (k0 + j) * 128 + n];
                    }
            v[j] = f2bf(acc);
        }
        uint4 pk;
        pk.x = (unsigned)v[0] | ((unsigned)v[1] << 16);
        pk.y = (unsigned)v[2] | ((unsigned)v[3] << 16);
        pk.z = (unsigned)v[4] | ((unsigned)v[5] << 16);
        pk.w = (unsigned)v[6] | ((unsigned)v[7] << 16);
        *(uint4*)&Wc1f[(long)rem * 8] = pk;
    } else {
        __shared__ float s_sum[32], s_sq[32];
        if (t < 32) { s_sum[t] = 0.0f; s_sq[t] = 0.0f; }
        __syncthreads();
        const float4* x4 = (const float4*)x;
        int total = NPAR * 32;
        int idx0 = (b - 760) * 256 + t;
        int g = idx0 & 31;
        float ls = 0.0f, lq = 0.0f;
        for (int idx = idx0; idx < total; idx += 256 * 256) {
            float4 v = x4[idx];
            ls += v.x + v.y + v.z + v.w;
            lq += v.x * v.x + v.y * v.y + v.z * v.z + v.w * v.w;
        }
        atomicAdd(&s_sum[g], ls);
        atomicAdd(&s_sq[g], lq);
        __syncthreads();
        int bank = ((b - 760) & 7) * 32;          // 8-way banked stats
        if (t < 32) { atomicAdd(&sum[bank + t], s_sum[t]); atomicAdd(&sq[bank + t], s_sq[t]); }
    }
}

// ---------------------------------------------------------------------------
// K2, 288 blocks: idx_tab+pidx27 build (needs grid32) / GN1 apply (needs stats)
__global__ void k2_kernel(const int* __restrict__ coords, const int* __restrict__ grid32,
                          int* __restrict__ idx_tab, int* __restrict__ pidx27,
                          const float* __restrict__ x, const float* __restrict__ sum,
                          const float* __restrict__ sq, const float* __restrict__ gamma,
                          const float* __restrict__ beta, unsigned short* __restrict__ y) {
    __shared__ float m_s[32], r_s[32];
    int b = blockIdx.x;
    if (b < 32) {
        int p = b * 256 + threadIdx.x;      // 8192 parents
        int cx = coords[p*3], cy = coords[p*3+1], cz = coords[p*3+2];
        int r27[27];
#pragma unroll
        for (int k = 0; k < 27; ++k) {
            int nx = cx + k / 9 - 1, ny = cy + (k / 3) % 3 - 1, nz = cz + k % 3 - 1;
            int r = -1;
            if ((unsigned)nx < 32u && (unsigned)ny < 32u && (unsigned)nz < 32u) {
                int g = grid32[(nx << 10) + (ny << 5) + nz];
                if ((unsigned)g < (unsigned)NPAR) r = g;
            }
            r27[k] = r;
            pidx27[k * NPAR + p] = r;
        }
#pragma unroll
        for (int k = 0; k < 27; ++k) {
            const int dx = k / 9 - 1, dy = (k / 3) % 3 - 1, dz = k % 3 - 1;
            int v[8];
#pragma unroll
            for (int o = 0; o < 8; ++o) {
                const int ex = ((o >> 2) & 1) + dx;
                const int ey = ((o >> 1) & 1) + dy;
                const int ez = (o & 1) + dz;
                const int ptap = ((ex >> 1) + 1) * 9 + ((ey >> 1) + 1) * 3 + ((ez >> 1) + 1);
                const int slot = ((ex & 1) << 2) + ((ey & 1) << 1) + (ez & 1);
                int r = r27[ptap];
                v[o] = (r >= 0) ? slot * NPAR + r : -1;
            }
            int4* dst = (int4*)&idx_tab[k * NCH + p * 8];
            dst[0] = make_int4(v[0], v[1], v[2], v[3]);
            dst[1] = make_int4(v[4], v[5], v[6], v[7]);
        }
    } else {
        int t = threadIdx.x;
        if (t < 32) {                       // fold 8 banks -> mean/rstd table
            float s = 0.0f, q = 0.0f;
#pragma unroll
            for (int c = 0; c < 8; ++c) { s += sum[c * 32 + t]; q += sq[c * 32 + t]; }
            float cnt = (float)NPAR * 4.0f;
            float mean = s / cnt;
            float var = q / cnt - mean * mean;
            m_s[t] = mean;
            r_s[t] = rsqrtf(var + EPS);
        }
        __syncthreads();
        const float4* x4 = (const float4*)x;
        uint2* y2 = (uint2*)y;
        const float4* g4 = (const float4*)gamma;
        const float4* b4 = (const float4*)beta;
        int total = NPAR * 32;
        for (int idx = (b - 32) * 256 + t; idx < total; idx += 256 * 256) {
            int c4 = idx & 31;
            float mean = m_s[c4], rstd = r_s[c4];
            float4 v = x4[idx];
            float4 gm = g4[c4];
            float4 bt = b4[c4];
            float a[4] = {v.x, v.y, v.z, v.w};
            float gg[4] = {gm.x, gm.y, gm.z, gm.w};
            float bb[4] = {bt.x, bt.y, bt.z, bt.w};
            unsigned short o[4];
#pragma unroll
            for (int i = 0; i < 4; ++i) {
                float tv = (a[i] - mean) * rstd * gg[i] + bb[i];
                o[i] = f2bf(tv / (1.0f + __expf(-tv)));
            }
            uint2 pk;
            pk.x = (unsigned)o[0] | ((unsigned)o[1] << 16);
            pk.y = (unsigned)o[2] | ((unsigned)o[3] << 16);
            y2[idx] = pk;
        }
    }
}

// ---------------------------------------------------------------------------
// GN2 apply + SiLU, in place on h1b; uint4 (8 bf16/thread), LDS stat table.
__global__ void gn_apply_bf16_kernel(unsigned short* __restrict__ x,
                                     const float* __restrict__ sum, const float* __restrict__ sq,
                                     const float* __restrict__ gamma, const float* __restrict__ beta,
                                     int nrows) {
    __shared__ float m_s[32], r_s[32];
    int t = threadIdx.x;
    if (t < 32) {
        float s = 0.0f, q = 0.0f;
#pragma unroll
        for (int c = 0; c < 8; ++c) { s += sum[c * 32 + t]; q += sq[c * 32 + t]; }
        float cnt = (float)nrows * 4.0f;
        float mean = s / cnt;
        float var = q / cnt - mean * mean;
        m_s[t] = mean;
        r_s[t] = rsqrtf(var + EPS);
    }
    __syncthreads();
    uint4* x4 = (uint4*)x;
    const float4* g4 = (const float4*)gamma;
    const float4* b4 = (const float4*)beta;
    int total = nrows * 16;                       // uint4 per 8 channels
    for (int idx = blockIdx.x * blockDim.x + t; idx < total;
         idx += gridDim.x * blockDim.x) {
        int c8 = idx & 15;                        // 16 uint4 per 128-ch row
        uint4 pk = x4[idx];
        float4 gm0 = g4[c8 * 2],     bt0 = b4[c8 * 2];
        float4 gm1 = g4[c8 * 2 + 1], bt1 = b4[c8 * 2 + 1];
        float m0 = m_s[c8 * 2], r0 = r_s[c8 * 2];
        float m1 = m_s[c8 * 2 + 1], r1 = r_s[c8 * 2 + 1];
        float gg[8] = {gm0.x, gm0.y, gm0.z, gm0.w, gm1.x, gm1.y, gm1.z, gm1.w};
        float bb[8] = {bt0.x, bt0.y, bt0.z, bt0.w, bt1.x, bt1.y, bt1.z, bt1.w};
        unsigned vv[4] = {pk.x, pk.y, pk.z, pk.w};
        unsigned short oo[8];
#pragma unroll
        for (int i = 0; i < 8; ++i) {
            float a = bf2f((unsigned short)(vv[i >> 1] >> ((i & 1) * 16)));
            float mm = (i < 4) ? m0 : m1;
            float rr = (i < 4) ? r0 : r1;
            float tv = (a - mm) * rr * gg[i] + bb[i];
            oo[i] = f2bf(tv / (1.0f + __expf(-tv)));
        }
        pk.x = (unsigned)oo[0] | ((unsigned)oo[1] << 16);
        pk.y = (unsigned)oo[2] | ((unsigned)oo[3] << 16);
        pk.z = (unsigned)oo[4] | ((unsigned)oo[5] << 16);
        pk.w = (unsigned)oo[6] | ((unsigned)oo[7] << 16);
        x4[idx] = pk;
    }
}

// ---------------------------------------------------------------------------
// Shared MFMA helpers — 1M x 4N wave grid (verified r5: conv2 68->59 µs).
// LDS A layout (per buffer): [grp(8)][ks(4)][r16(16)][cch(4)][8 shorts].
// Bank-conflict fix (verified: SQ_LDS_BANK_CONFLICT 3.54M -> 0): source-side
// XOR cch^((r16>>1)&3), undone on ds_read (swz = quad^((l16>>1)&3)).
__device__ __forceinline__ void mfma_phase(
    const unsigned short* __restrict__ Abuf, short8 (&bfr)[2][4],
    floatx4 (&acc)[8][2], int aswz) {
#pragma unroll
    for (int ks = 0; ks < 4; ++ks) {
        short8 afr[8];
#pragma unroll
        for (int mt = 0; mt < 8; ++mt)
            afr[mt] = *(const short8*)&Abuf[(mt << 11) + (ks << 9) + aswz];
#pragma unroll
        for (int mt = 0; mt < 8; ++mt)
#pragma unroll
            for (int nt = 0; nt < 2; ++nt)
                acc[mt][nt] = __builtin_amdgcn_mfma_f32_16x16x32_bf16(
                    afr[mt], bfr[nt][ks], acc[mt][nt], 0, 0, 0);
    }
}
__device__ __forceinline__ void loadB(const unsigned short* __restrict__ Wtap,
                                      short8 (&bfr)[2][4], int wn, int lane) {
#pragma unroll
    for (int nt = 0; nt < 2; ++nt)
#pragma unroll
        for (int ks = 0; ks < 4; ++ks)
            bfr[nt][ks] = *(const short8*)&Wtap[(((wn * 2 + nt) << 2) + ks) * 512 + (lane << 3)];
}
__device__ __forceinline__ void stageA(const unsigned short* __restrict__ Ag,
                                       int iv0, int iv1, const unsigned short* zsrc,
                                       unsigned short* __restrict__ buf,
                                       int base0, int base1, int cchOff) {
    const unsigned short* g0 = (iv0 >= 0) ? Ag + (long)iv0 * 128 : zsrc;
    const unsigned short* g1 = (iv1 >= 0) ? Ag + (long)iv1 * 128 : zsrc;
#pragma unroll
    for (int i = 0; i < 4; ++i) glds16(g0 + i * 32 + cchOff, &buf[base0 + i * 512]);
#pragma unroll
    for (int i = 0; i < 4; ++i) glds16(g1 + i * 32 + cchOff, &buf[base1 + i * 512]);
}

// ---------------------------------------------------------------------------
// CONV1 FOLDED — 2x-unrolled slot loop, ping-pong B register sets, 1Mx4N wave
// grid, LDS-bounce coalesced epilogue, 8-way banked GN2 stat atomics.
__global__ void __launch_bounds__(256, 2) conv1_fold_kernel(
    const unsigned short* __restrict__ Ag, const unsigned short* __restrict__ Wc1f,
    const float* __restrict__ bias, const int* __restrict__ pidx27,
    unsigned short* __restrict__ outp, const float* __restrict__ zpage,
    float* __restrict__ gsum, float* __restrict__ gsq) {
    __shared__ unsigned short A_lds[2][16384];   // 2 x 32 KB

    int t = threadIdx.x;
    int o  = blockIdx.x & 7;
    int P0 = (blockIdx.x >> 3) << 7;            // 128 parents per block
    const unsigned short* Wb = Wc1f + ((long)o << 17);
    int wv = t >> 6, lane = t & 63, quad = lane >> 4, l16 = lane & 15;
    int wn = wv;                                 // 1M x 4N: wave owns 32 cols
    int r16 = lane >> 2, cch = lane & 3;
    int c0 = wv * 2, c1 = wv * 2 + 1;
    int row0 = ((c0 >> 2) << 6) + ((c0 & 3) << 4) + r16;
    int row1 = ((c1 >> 2) << 6) + ((c1 & 3) << 4) + r16;
    int base0 = ((c0 >> 2) << 13) + ((c0 & 3) << 11);
    int base1 = ((c1 >> 2) << 13) + ((c1 & 3) << 11);
    int cchOff = (cch ^ ((r16 >> 1) & 3)) << 3;            // swizzled source chunk
    int aswz = (l16 << 5) + ((quad ^ ((l16 >> 1) & 3)) << 3);  // swizzled read
    const unsigned short* zsrc = (const unsigned short*)zpage;

    floatx4 acc[8][2];
#pragma unroll
    for (int mt = 0; mt < 8; ++mt)
#pragma unroll
        for (int nt = 0; nt < 2; ++nt)
            acc[mt][nt] = (floatx4){0.f, 0.f, 0.f, 0.f};
    short8 bA[2][4], bB[2][4];

    // ---- prolog: slot 0 A -> buf0, slot 0 B -> bA
    stageA(Ag, pidx27[k27_of(o, 0) * NPAR + P0 + row0],
               pidx27[k27_of(o, 0) * NPAR + P0 + row1], zsrc, A_lds[0], base0, base1, cchOff);
    loadB(Wb, bA, wn, lane);
    int nv0 = pidx27[k27_of(o, 1) * NPAR + P0 + row0];
    int nv1 = pidx27[k27_of(o, 1) * NPAR + P0 + row1];
    __syncthreads();

#pragma unroll 1
    for (int s = 0; s < 8; s += 2) {
        stageA(Ag, nv0, nv1, zsrc, A_lds[1], base0, base1, cchOff);
        loadB(Wb + ((long)(s + 1) << 14), bB, wn, lane);
        if (s + 2 < 8) {
            nv0 = pidx27[k27_of(o, s + 2) * NPAR + P0 + row0];
            nv1 = pidx27[k27_of(o, s + 2) * NPAR + P0 + row1];
        }
        mfma_phase(A_lds[0], bA, acc, aswz);
        __syncthreads();
        if (s + 2 < 8) {
            stageA(Ag, nv0, nv1, zsrc, A_lds[0], base0, base1, cchOff);
            loadB(Wb + ((long)(s + 2) << 14), bA, wn, lane);
            if (s + 3 < 8) {
                nv0 = pidx27[k27_of(o, s + 3) * NPAR + P0 + row0];
                nv1 = pidx27[k27_of(o, s + 3) * NPAR + P0 + row1];
            }
        }
        mfma_phase(A_lds[1], bB, acc, aswz);
        __syncthreads();
    }

    // ---- epilogue: bias + bf16 round + GN2 stats (regs) -> LDS bounce
    unsigned short* lds_s = (unsigned short*)A_lds;   // 32 KB bounce (buf 0)
    float* sred = (float*)(&A_lds[1][0]);             // 64 f reduction (buf 1)
    float s_[2] = {0.f, 0.f}, q_[2] = {0.f, 0.f};
#pragma unroll
    for (int nt = 0; nt < 2; ++nt) {
        int col = wn * 32 + nt * 16 + l16;
        float bv = bias[col];
#pragma unroll
        for (int mt = 0; mt < 8; ++mt) {
#pragma unroll
            for (int r = 0; r < 4; ++r) {
                int row = mt * 16 + quad * 4 + r;
                float v = acc[mt][nt][r] + bv;
                unsigned short u = f2bf(v);
                lds_s[row * 128 + (col ^ (quad << 4))] = u;
                float vr = bf2f(u);
                s_[nt] += vr;
                q_[nt] += vr * vr;
            }
        }
    }
    if (t < 64) sred[t] = 0.0f;
    __syncthreads();
    // coalesced stores: 8 iters x 256 threads x 16B = 32 KB
#pragma unroll
    for (int it = 0; it < 8; ++it) {
        int f = it * 256 + t;
        int row = f >> 4, c = (f & 15) * 8;
        int sw = ((row >> 2) & 3) << 4;
        uint4 v = *(const uint4*)&lds_s[row * 128 + (c ^ sw)];
        *(uint4*)&outp[((long)o * NPAR + P0 + row) * 128 + c] = v;
    }
#pragma unroll
    for (int nt = 0; nt < 2; ++nt) {
        int g = (wn * 32 + nt * 16 + l16) >> 2;
        atomicAdd(&sred[g], s_[nt]);
        atomicAdd(&sred[32 + g], q_[nt]);
    }
    __syncthreads();
    int bank = (blockIdx.x & 7) * 32;             // 8-way banked stats
    if (t < 32) { atomicAdd(&gsum[bank + t], sred[t]); atomicAdd(&gsq[bank + t], sred[32 + t]); }
}

// ---------------------------------------------------------------------------
// CONV2 — 2x-unrolled tap loop, ping-pong B register sets, 1Mx4N wave grid,
// LDS-bounce coalesced epilogue.
__global__ void __launch_bounds__(256, 2) conv2_kernel(
    const unsigned short* __restrict__ Ag, const unsigned short* __restrict__ Wp,
    const float* __restrict__ bias, const int* __restrict__ idx_tab,
    const float* __restrict__ resid, float* __restrict__ outp,
    const float* __restrict__ zpage) {
    __shared__ unsigned short A_lds[2][16384];   // 2 x 32 KB

    int t = threadIdx.x;
    int R0 = blockIdx.x * 128;
    int wv = t >> 6, lane = t & 63, quad = lane >> 4, l16 = lane & 15;
    int wn = wv;                                 // 1M x 4N: wave owns 32 cols
    int r16 = lane >> 2, cch = lane & 3;
    int c0 = wv * 2, c1 = wv * 2 + 1;
    int row0 = ((c0 >> 2) << 6) + ((c0 & 3) << 4) + r16;
    int row1 = ((c1 >> 2) << 6) + ((c1 & 3) << 4) + r16;
    int base0 = ((c0 >> 2) << 13) + ((c0 & 3) << 11);
    int base1 = ((c1 >> 2) << 13) + ((c1 & 3) << 11);
    int cchOff = (cch ^ ((r16 >> 1) & 3)) << 3;            // swizzled source chunk
    int aswz = (l16 << 5) + ((quad ^ ((l16 >> 1) & 3)) << 3);  // swizzled read
    const unsigned short* zsrc = (const unsigned short*)zpage;

    floatx4 acc[8][2];
#pragma unroll
    for (int mt = 0; mt < 8; ++mt)
#pragma unroll
        for (int nt = 0; nt < 2; ++nt)
            acc[mt][nt] = (floatx4){0.f, 0.f, 0.f, 0.f};
    short8 bA[2][4], bB[2][4];

    // ---- prolog: tap 0 A -> buf0, tap 0 B -> bA
    stageA(Ag, idx_tab[R0 + row0], idx_tab[R0 + row1], zsrc, A_lds[0], base0, base1, cchOff);
    loadB(Wp, bA, wn, lane);
    int nv0 = idx_tab[NCH + R0 + row0], nv1 = idx_tab[NCH + R0 + row1];
    __syncthreads();

#pragma unroll 1
    for (int k = 0; k < 27; k += 2) {
        if (k + 1 < 27) {
            stageA(Ag, nv0, nv1, zsrc, A_lds[1], base0, base1, cchOff);
            loadB(Wp + ((long)(k + 1) << 14), bB, wn, lane);
            if (k + 2 < 27) {
                nv0 = idx_tab[(k + 2) * NCH + R0 + row0];
                nv1 = idx_tab[(k + 2) * NCH + R0 + row1];
            }
        }
        mfma_phase(A_lds[0], bA, acc, aswz);
        __syncthreads();
        if (k + 1 < 27) {
            if (k + 2 < 27) {
                stageA(Ag, nv0, nv1, zsrc, A_lds[0], base0, base1, cchOff);
                loadB(Wp + ((long)(k + 2) << 14), bA, wn, lane);
                if (k + 3 < 27) {
                    nv0 = idx_tab[(k + 3) * NCH + R0 + row0];
                    nv1 = idx_tab[(k + 3) * NCH + R0 + row1];
                }
            }
            mfma_phase(A_lds[1], bB, acc, aswz);
            __syncthreads();
        }
    }

    // ---- epilogue: bias + resid (regs) -> LDS bounce -> coalesced float4
    float* lds_f = (float*)A_lds;                // 64 KB = 128x128 fp32 exact
#pragma unroll
    for (int nt = 0; nt < 2; ++nt) {
        int col = wn * 32 + nt * 16 + l16;
        float bv = bias[col];
#pragma unroll
        for (int mt = 0; mt < 8; ++mt) {
#pragma unroll
            for (int r = 0; r < 4; ++r) {
                int row = mt * 16 + quad * 4 + r;
                long R = (long)R0 + row;
                float v = acc[mt][nt][r] + bv + resid[(R >> 3) * 128 + col];
                lds_f[row * 128 + (col ^ (quad << 4))] = v;
            }
        }
    }
    __syncthreads();
    // coalesced stores: 16 iters x 256 threads x 16B = 64 KB
#pragma unroll
    for (int it = 0; it < 16; ++it) {
        int f = it * 256 + t;
        int row = f >> 5, c = (f & 31) * 4;
        int sw = ((row >> 2) & 3) << 4;
        float4 v = *(const float4*)&lds_f[row * 128 + (c ^ sw)];
        *(float4*)&outp[((long)R0 + row) * 128 + c] = v;
    }
}

// ---------------------------------------------------------------------------
extern "C" void kernel_launch(void* const* d_in, const int* in_sizes, int n_in,
                              void* d_out, int out_size, void* d_ws, size_t ws_size,
                              hipStream_t stream) {
    const float* feats  = (const float*)d_in[0];
    const float* gamma1 = (const float*)d_in[1];
    const float* beta1  = (const float*)d_in[2];
    const float* W1     = (const float*)d_in[3];
    const float* b1     = (const float*)d_in[4];
    const float* gamma2 = (const float*)d_in[5];
    const float* beta2  = (const float*)d_in[6];
    const float* W2     = (const float*)d_in[7];
    const float* b2     = (const float*)d_in[8];
    const int*   coords = (const int*)d_in[9];
    float* out = (float*)d_out;   // 65536 x 128 fp32 (written only by conv2)

    char* ws = (char*)d_ws;
    unsigned short* h0b  = (unsigned short*)(ws);                    // 2 MB
    unsigned short* h1b  = (unsigned short*)(ws + (2u << 20));       // 16 MB, (o,p) layout
    unsigned short* Wc1f = (unsigned short*)(ws + (18u << 20));      // 2 MB
    unsigned short* Wp2  = (unsigned short*)(ws + (20u << 20));      // 864 KB
    int*   grid32        = (int*)  (ws + (21u << 20));               // 128 KB
    float* stats         = (float*)(ws + (21u << 20) + 131072);      // 4 KB (8-banked)
    float* zpage         = (float*)(ws + (21u << 20) + 131072 + 4096); // 512 B
    int*   idx_tab       = (int*)  (ws + (22u << 20));               // 7.08 MB
    int*   pidx27        = (int*)  (ws + (30u << 20));               // 864 KB

    // zero stats (1024 f) + zpage (128 f) in one async memset
    hipMemsetAsync(stats, 0, 4096 + 512, stream);

    // stats layout: [0,256) sum1 banks, [256,512) sq1, [512,768) sum2, [768,1024) sq2
    k1_kernel<<<1016, 256, 0, stream>>>(coords, grid32, feats, stats + 0, stats + 256,
                                        W1, W2, Wc1f, Wp2);
    k2_kernel<<<288, 256, 0, stream>>>(coords, grid32, idx_tab, pidx27,
                                       feats, stats + 0, stats + 256, gamma1, beta1, h0b);

    // conv1 folded -> bf16 h1b in (o,p) layout + fused GN2 stats (banked)
    conv1_fold_kernel<<<8 * (NPAR / 128), 256, 0, stream>>>(h0b, Wc1f, b1, pidx27,
                                                            h1b, zpage,
                                                            stats + 512, stats + 768);

    gn_apply_bf16_kernel<<<2048, 256, 0, stream>>>(h1b, stats + 512, stats + 768,
                                                   gamma2, beta2, NCH);

    // conv2 (27 taps over children) -> fp32 out + residual repeat(feats,8)
    conv2_kernel<<<NCH / 128, 256, 0, stream>>>(h1b, Wp2, b2, idx_tab,
                                                feats, out, zpage);
}